// Round 1
// baseline (436.252 us; speedup 1.0000x reference)
//
#include <hip/hip_runtime.h>

// Brute N^2 neighborlist (upper-triangular pairs), N=6000.
// Outputs (flat f32, concatenated):
//   [0,P)      : i index or -1
//   [P,2P)     : j index or -1
//   [2P,3P)    : d_ij or 0
//   [3P,6P)    : r_ij (x,y,z) or 0
// Mask math replicates numpy bitwise: fmod-based floored remainder,
// sequential sum of squares, exact sqrt; no fp contraction (explicit _rn
// intrinsics) so the d<=0.5 mask can't flip vs the reference.

constexpr int       NPART  = 6000;
constexpr long long NPAIRS = (long long)NPART * (NPART - 1) / 2;  // 17,997,000
constexpr float     CUT    = 0.5f;

__global__ __launch_bounds__(256) void nbl_kernel(
    const float* __restrict__ pos,      // [N,3]
    const float* __restrict__ boxv,     // [3,3], diag read
    const int*  __restrict__ is_per,    // scalar
    float* __restrict__ out)
{
    long long p = (long long)blockIdx.x * blockDim.x + threadIdx.x;
    if (p >= NPAIRS) return;

    // Invert triangular index: pairs before row i: S(i) = i*(N-1) - i*(i-1)/2
    // i = floor(((2N-1) - sqrt((2N-1)^2 - 8p)) / 2), then integer fixup.
    const double twoNm1 = 2.0 * NPART - 1.0;
    double disc = twoNm1 * twoNm1 - 8.0 * (double)p;
    int i = (int)((twoNm1 - sqrt(disc)) * 0.5);
    if (i < 0) i = 0;
    if (i > NPART - 2) i = NPART - 2;
    while ((long long)(i + 1) * (NPART - 1) - ((long long)(i + 1) * i) / 2 <= p) ++i;
    while ((long long)i * (NPART - 1) - ((long long)i * (i - 1)) / 2 > p) --i;
    long long Si = (long long)i * (NPART - 1) - ((long long)i * (i - 1)) / 2;
    int j = i + 1 + (int)(p - Si);

    float xi = pos[3 * i + 0], yi = pos[3 * i + 1], zi = pos[3 * i + 2];
    float xj = pos[3 * j + 0], yj = pos[3 * j + 1], zj = pos[3 * j + 2];
    float rx = __fsub_rn(xi, xj);
    float ry = __fsub_rn(yi, yj);
    float rz = __fsub_rn(zi, zj);

    if (*is_per) {
        float bx = boxv[0], by = boxv[4], bz = boxv[8];
        float hx = __fmul_rn(bx, 0.5f);
        float hy = __fmul_rn(by, 0.5f);
        float hz = __fmul_rn(bz, 0.5f);
        float t;
        // numpy remainder: res = fmod(x,b); if (res!=0 && sign(res)!=sign(b)) res += b;
        t = fmodf(__fadd_rn(rx, hx), bx);
        if (t != 0.0f && ((t < 0.0f) != (bx < 0.0f))) t = __fadd_rn(t, bx);
        rx = __fsub_rn(t, hx);
        t = fmodf(__fadd_rn(ry, hy), by);
        if (t != 0.0f && ((t < 0.0f) != (by < 0.0f))) t = __fadd_rn(t, by);
        ry = __fsub_rn(t, hy);
        t = fmodf(__fadd_rn(rz, hz), bz);
        if (t != 0.0f && ((t < 0.0f) != (bz < 0.0f))) t = __fadd_rn(t, bz);
        rz = __fsub_rn(t, hz);
    }

    float s = __fadd_rn(__fadd_rn(__fmul_rn(rx, rx), __fmul_rn(ry, ry)),
                        __fmul_rn(rz, rz));
    float d = __fsqrt_rn(s);
    bool in = (d <= CUT);

    out[p]              = in ? (float)i : -1.0f;
    out[NPAIRS + p]     = in ? (float)j : -1.0f;
    out[2 * NPAIRS + p] = in ? d : 0.0f;
    long long rbase = 3 * NPAIRS + 3 * p;
    out[rbase + 0] = in ? rx : 0.0f;
    out[rbase + 1] = in ? ry : 0.0f;
    out[rbase + 2] = in ? rz : 0.0f;
}

extern "C" void kernel_launch(void* const* d_in, const int* in_sizes, int n_in,
                              void* d_out, int out_size, void* d_ws, size_t ws_size,
                              hipStream_t stream) {
    const float* pos    = (const float*)d_in[0];
    const float* boxv   = (const float*)d_in[1];
    const int*   is_per = (const int*)d_in[2];
    float* out = (float*)d_out;

    const int block = 256;
    const long long grid = (NPAIRS + block - 1) / block;  // 70,301 blocks
    nbl_kernel<<<dim3((unsigned)grid), dim3(block), 0, stream>>>(pos, boxv, is_per, out);
}

// Round 2
// 434.669 us; speedup vs baseline: 1.0036x; 1.0036x over previous
//
#include <hip/hip_runtime.h>

// Brute N^2 neighborlist (upper-triangular pairs), N=6000, P=17,997,000.
// Output layout (flat f32): [0,P) i | [P,2P) j | [2P,3P) d | [3P,6P) r_xyz.
// Each thread handles 4 consecutive pairs -> all stores are aligned float4.
// PBC wrap replicates numpy remainder bitwise via Sterbenz-exact branches
// (valid since |r| < box and box > 0). No fp contraction on the distance
// math (explicit _rn intrinsics) so the d<=0.5 mask cannot flip vs numpy.

constexpr int NPART  = 6000;
constexpr int NPAIRS = 17997000;          // N*(N-1)/2, divisible by 4
constexpr float CUT  = 0.5f;

__device__ __forceinline__ int row_start(int i) {
    // pairs before row i: S(i) = i*(N-1) - i*(i-1)/2   (fits int32)
    return i * (NPART - 1) - (i * (i - 1)) / 2;
}

// numpy remainder(r+h, b) - h for |r| < b, b > 0, h = b/2. Bitwise-exact:
//  v>=b : fmod(v,b) = v-b exactly (Sterbenz, b<=v<2b), __fsub_rn exact
//  v<0  : fmod(v,b) = v (|v|<b), numpy then does v += b (rounded add)
//  else : unchanged.  v==-0.0 falls through (matches numpy r!=0 check).
__device__ __forceinline__ float pbc_wrap(float r, float b, float h) {
    float v = __fadd_rn(r, h);
    if (v >= b)      v = __fsub_rn(v, b);
    else if (v < 0.f) v = __fadd_rn(v, b);
    return __fsub_rn(v, h);
}

__global__ __launch_bounds__(256) void nbl_kernel(
    const float* __restrict__ pos,     // [N,3]
    const float* __restrict__ boxv,    // [3,3]
    const int*  __restrict__ is_per,
    float* __restrict__ out)
{
    int p = (blockIdx.x * blockDim.x + threadIdx.x) * 4;
    if (p >= NPAIRS) return;

    // invert triangular index (fp32 estimate + int32 fixup)
    const float A = 2.0f * NPART - 1.0f;   // 11999
    float disc = A * A - 8.0f * (float)p;
    int i = (int)((A - sqrtf(disc)) * 0.5f);
    if (i < 0) i = 0;
    if (i > NPART - 2) i = NPART - 2;
    while (i < NPART - 2 && row_start(i + 1) <= p) ++i;
    while (i > 0 && row_start(i) > p) --i;
    int j = i + 1 + (p - row_start(i));

    const bool per = (*is_per != 0);
    const float bx = boxv[0], by = boxv[4], bz = boxv[8];
    const float hx = __fmul_rn(bx, 0.5f);
    const float hy = __fmul_rn(by, 0.5f);
    const float hz = __fmul_rn(bz, 0.5f);

    float xi = pos[3 * i + 0], yi = pos[3 * i + 1], zi = pos[3 * i + 2];

    float oi[4], oj[4], od[4], orr[12];

    #pragma unroll
    for (int k = 0; k < 4; ++k) {
        float xj = pos[3 * j + 0], yj = pos[3 * j + 1], zj = pos[3 * j + 2];
        float rx = __fsub_rn(xi, xj);
        float ry = __fsub_rn(yi, yj);
        float rz = __fsub_rn(zi, zj);
        if (per) {
            rx = pbc_wrap(rx, bx, hx);
            ry = pbc_wrap(ry, by, hy);
            rz = pbc_wrap(rz, bz, hz);
        }
        float s = __fadd_rn(__fadd_rn(__fmul_rn(rx, rx), __fmul_rn(ry, ry)),
                            __fmul_rn(rz, rz));
        float d = __fsqrt_rn(s);
        bool in = (d <= CUT);

        oi[k] = in ? (float)i : -1.0f;
        oj[k] = in ? (float)j : -1.0f;
        od[k] = in ? d : 0.0f;
        orr[3 * k + 0] = in ? rx : 0.0f;
        orr[3 * k + 1] = in ? ry : 0.0f;
        orr[3 * k + 2] = in ? rz : 0.0f;

        // advance to next upper-triangular pair
        ++j;
        if (j == NPART) { ++i; j = i + 1;
            xi = pos[3 * i + 0]; yi = pos[3 * i + 1]; zi = pos[3 * i + 2]; }
    }

    *(float4*)(out + p)              = make_float4(oi[0], oi[1], oi[2], oi[3]);
    *(float4*)(out + NPAIRS + p)     = make_float4(oj[0], oj[1], oj[2], oj[3]);
    *(float4*)(out + 2 * NPAIRS + p) = make_float4(od[0], od[1], od[2], od[3]);
    float* rb = out + 3 * NPAIRS + 3 * p;   // element offset % 4 == 0
    *(float4*)(rb + 0) = make_float4(orr[0], orr[1], orr[2],  orr[3]);
    *(float4*)(rb + 4) = make_float4(orr[4], orr[5], orr[6],  orr[7]);
    *(float4*)(rb + 8) = make_float4(orr[8], orr[9], orr[10], orr[11]);
}

extern "C" void kernel_launch(void* const* d_in, const int* in_sizes, int n_in,
                              void* d_out, int out_size, void* d_ws, size_t ws_size,
                              hipStream_t stream) {
    const float* pos    = (const float*)d_in[0];
    const float* boxv   = (const float*)d_in[1];
    const int*   is_per = (const int*)d_in[2];
    float* out = (float*)d_out;

    const int block = 256;
    const int nthreads = NPAIRS / 4;                  // 4,499,250
    const int grid = (nthreads + block - 1) / block;  // 17,576
    nbl_kernel<<<grid, block, 0, stream>>>(pos, boxv, is_per, out);
}

// Round 3
// 432.169 us; speedup vs baseline: 1.0094x; 1.0058x over previous
//
#include <hip/hip_runtime.h>

// Brute N^2 neighborlist (upper-triangular pairs), N=6000, P=17,997,000.
// Output layout (flat f32): [0,P) i | [P,2P) j | [2P,3P) d | [3P,6P) r_xyz.
//
// R3: every global store is wave-contiguous. Each block handles 1024 pairs
// (256 thr x 4). The r-triples (12 floats/thread, stride-48 if stored
// directly -> 3x write transactions) are redistributed through a 12 KB LDS
// buffer in final layout, then streamed out as lane-contiguous float4s.
// PBC wrap replicates numpy remainder bitwise (Sterbenz-exact branches,
// valid since |r| < box, box > 0); explicit _rn intrinsics forbid
// contraction so the d<=0.5 mask cannot flip vs numpy.

constexpr int NPART  = 6000;
constexpr int NPAIRS = 17997000;     // N*(N-1)/2; % 1024 == 200, % 4 == 0
constexpr float CUT  = 0.5f;
constexpr int TPB = 256;
constexpr int PPT = 4;               // pairs per thread
constexpr int PPB = TPB * PPT;       // 1024 pairs per block

__device__ __forceinline__ int row_start(int i) {
    // pairs before row i: S(i) = i*(N-1) - i*(i-1)/2  (fits int32)
    return i * (NPART - 1) - (i * (i - 1)) / 2;
}

// numpy remainder(r+h, b) - h for |r| < b, b > 0, h = b/2 — bitwise-exact.
__device__ __forceinline__ float pbc_wrap(float r, float b, float h) {
    float v = __fadd_rn(r, h);
    if (v >= b)       v = __fsub_rn(v, b);
    else if (v < 0.f) v = __fadd_rn(v, b);
    return __fsub_rn(v, h);
}

__global__ __launch_bounds__(TPB) void nbl_kernel(
    const float* __restrict__ pos,     // [N,3]
    const float* __restrict__ boxv,    // [3,3]
    const int*  __restrict__ is_per,
    float* __restrict__ out)
{
    __shared__ float lds_r[PPB * 3];   // 12,288 B, final r layout for this block

    const int t     = threadIdx.x;
    const int pbase = blockIdx.x * PPB;
    const int p     = pbase + t * PPT;
    // nvalid (pairs in this block) is 1024 or 200 — always % 4 == 0, so each
    // thread's 4 pairs are entirely valid or entirely invalid.
    const int nvalid = (NPAIRS - pbase < PPB) ? (NPAIRS - pbase) : PPB;

    if (t * PPT < nvalid) {
        // invert triangular index (fp32 estimate + int fixup)
        const float A = 2.0f * NPART - 1.0f;   // 11999
        float disc = A * A - 8.0f * (float)p;
        int i = (int)((A - sqrtf(disc)) * 0.5f);
        if (i < 0) i = 0;
        if (i > NPART - 2) i = NPART - 2;
        while (i < NPART - 2 && row_start(i + 1) <= p) ++i;
        while (i > 0 && row_start(i) > p) --i;
        int j = i + 1 + (p - row_start(i));

        const bool per = (*is_per != 0);
        const float bx = boxv[0], by = boxv[4], bz = boxv[8];
        const float hx = __fmul_rn(bx, 0.5f);
        const float hy = __fmul_rn(by, 0.5f);
        const float hz = __fmul_rn(bz, 0.5f);

        float xi = pos[3 * i + 0], yi = pos[3 * i + 1], zi = pos[3 * i + 2];

        float oi[4], oj[4], od[4], orr[12];

        #pragma unroll
        for (int k = 0; k < 4; ++k) {
            float xj = pos[3 * j + 0], yj = pos[3 * j + 1], zj = pos[3 * j + 2];
            float rx = __fsub_rn(xi, xj);
            float ry = __fsub_rn(yi, yj);
            float rz = __fsub_rn(zi, zj);
            if (per) {
                rx = pbc_wrap(rx, bx, hx);
                ry = pbc_wrap(ry, by, hy);
                rz = pbc_wrap(rz, bz, hz);
            }
            float s = __fadd_rn(__fadd_rn(__fmul_rn(rx, rx), __fmul_rn(ry, ry)),
                                __fmul_rn(rz, rz));
            float d = __fsqrt_rn(s);
            bool in = (d <= CUT);

            oi[k] = in ? (float)i : -1.0f;
            oj[k] = in ? (float)j : -1.0f;
            od[k] = in ? d : 0.0f;
            orr[3 * k + 0] = in ? rx : 0.0f;
            orr[3 * k + 1] = in ? ry : 0.0f;
            orr[3 * k + 2] = in ? rz : 0.0f;

            // advance to next upper-triangular pair
            ++j;
            if (j == NPART) { ++i; j = i + 1;
                xi = pos[3 * i + 0]; yi = pos[3 * i + 1]; zi = pos[3 * i + 2]; }
        }

        // stage r-triples in LDS in final layout (16B-aligned b128 writes)
        float4* lv = (float4*)(lds_r + 12 * t);
        lv[0] = make_float4(orr[0], orr[1], orr[2],  orr[3]);
        lv[1] = make_float4(orr[4], orr[5], orr[6],  orr[7]);
        lv[2] = make_float4(orr[8], orr[9], orr[10], orr[11]);

        // i/j/d streams: already wave-contiguous float4
        *(float4*)(out + p)              = make_float4(oi[0], oi[1], oi[2], oi[3]);
        *(float4*)(out + NPAIRS + p)     = make_float4(oj[0], oj[1], oj[2], oj[3]);
        *(float4*)(out + 2 * NPAIRS + p) = make_float4(od[0], od[1], od[2], od[3]);
    }

    __syncthreads();

    // stream r out lane-contiguously: block owns floats [3*pbase, 3*pbase+3*nvalid)
    // 3*pbase % 4 == 0, 3*nvalid % 4 == 0 -> float4 granularity exact.
    const int nf4 = (3 * nvalid) / 4;                 // 768 or 150
    float4* rdst = (float4*)(out + 3 * NPAIRS + 3 * pbase);
    const float4* rsrc = (const float4*)lds_r;
    #pragma unroll
    for (int s = 0; s < 3; ++s) {
        int q = t + TPB * s;
        if (q < nf4) rdst[q] = rsrc[q];
    }
}

extern "C" void kernel_launch(void* const* d_in, const int* in_sizes, int n_in,
                              void* d_out, int out_size, void* d_ws, size_t ws_size,
                              hipStream_t stream) {
    const float* pos    = (const float*)d_in[0];
    const float* boxv   = (const float*)d_in[1];
    const int*   is_per = (const int*)d_in[2];
    float* out = (float*)d_out;

    const int grid = (NPAIRS + PPB - 1) / PPB;   // 17,576
    nbl_kernel<<<grid, TPB, 0, stream>>>(pos, boxv, is_per, out);
}